// Round 1
// 1168.992 us; speedup vs baseline: 1.1703x; 1.1703x over previous
//
#include <hip/hip_runtime.h>
#include <cstdint>
#include <cstddef>

// ---------------------------------------------------------------------------
// DPN_88965952569844: out = relu(x@W1^T + b1) -> concat(x,h1) @ W2^T + b2
// B=4096, D_IN=4096, HID=16384, OUT=1000.  fp32 in/out, bf16 MFMA compute.
// R4: replace both 128^2 2-barrier GEMMs with a 256^2 deep-pipeline kernel:
//     - 8 waves (2Mx4N), per-wave 128x64 output, acc[8][4] f32x4
//     - BK=32, FOUR LDS buffers (128 KiB), stage(t+3) issued 3 tiles ahead
//     - counted s_waitcnt vmcnt(8) per tile (T4) -- never drains to 0 in the
//       main loop; epilogue peels vmcnt(4)/vmcnt(0)
//     - s_setprio(1) around the 32-MFMA cluster (T5)
//     - keeps R2's XOR chunk swizzle (0 bank conflicts, verified) and the
//       proven fragment/epilogue layout
//     - GEMM1: bijective XCD swizzle, 8x8-tile panels per XCD (T1)
//     - GEMM2: 256^2 tiles cut staging bytes/FLOP 4x vs 128^2; split-K=4
//       -> 256 blocks = exactly 1/CU
// ---------------------------------------------------------------------------

using u16 = unsigned short;

typedef __bf16 bf16x8 __attribute__((ext_vector_type(8)));
typedef float  f32x4  __attribute__((ext_vector_type(4)));

#define GLOBAL_AS __attribute__((address_space(1)))
#define LDS_AS    __attribute__((address_space(3)))

__device__ __forceinline__ void async_load16(const void* gp, void* lp) {
    __builtin_amdgcn_global_load_lds((GLOBAL_AS void*)gp, (LDS_AS void*)lp, 16, 0, 0);
}

__device__ __forceinline__ u16 f2bf(float f) {
    union { float f; uint32_t u; } c; c.f = f;
    uint32_t u = c.u;
    u += 0x7FFFu + ((u >> 16) & 1u);   // round-to-nearest-even
    return (u16)(u >> 16);
}

// LDS swizzle: tile row r holds its 4 16B-chunks permuted: phys = q ^ ((r>>1)&3)
__device__ __forceinline__ int swz(int q, int row) { return q ^ ((row >> 1) & 3); }

// ---------------------------------------------------------------------------
// fp32 -> bf16 conversion kernels (unchanged)
// ---------------------------------------------------------------------------

__global__ void cvt_x_kernel(const float* __restrict__ x, u16* __restrict__ dst) {
    int idx = blockIdx.x * 256 + threadIdx.x;
    int row = idx >> 10;
    int c4  = (idx & 1023) << 2;
    float4 v = *(const float4*)&x[(size_t)row * 4096 + c4];
    ushort4 o;
    o.x = f2bf(v.x); o.y = f2bf(v.y); o.z = f2bf(v.z); o.w = f2bf(v.w);
    *(ushort4*)&dst[(size_t)row * 20480 + c4] = o;
}

__global__ void cvt_flat_kernel(const float* __restrict__ src, u16* __restrict__ dst) {
    int idx = blockIdx.x * 256 + threadIdx.x;
    float4 v = *(const float4*)&src[(size_t)idx * 4];
    ushort4 o;
    o.x = f2bf(v.x); o.y = f2bf(v.y); o.z = f2bf(v.z); o.w = f2bf(v.w);
    *(ushort4*)&dst[(size_t)idx * 4] = o;
}

__global__ void cvt_w2_kernel(const float* __restrict__ src, u16* __restrict__ dst) {
    int idx = blockIdx.x * 256 + threadIdx.x;
    int row = idx / 5120;
    int c4  = (idx % 5120) * 4;
    ushort4 o;
    if (row < 1000) {
        float4 v = *(const float4*)&src[(size_t)row * 20480 + c4];
        o.x = f2bf(v.x); o.y = f2bf(v.y); o.z = f2bf(v.z); o.w = f2bf(v.w);
    } else {
        o.x = 0; o.y = 0; o.z = 0; o.w = 0;
    }
    *(ushort4*)&dst[(size_t)row * 20480 + c4] = o;
}

// ---------------------------------------------------------------------------
// 256x256 deep-pipelined NT bf16 GEMM: C[M,N] = A[M,K'] * B[N,K']^T.
// blockIdx.z selects the K-chunk (A/B advanced by kz*K, partials by c_slab).
// EPI 0: C = bf16(relu(acc + bias[n])), C is u16*
// EPI 1: C = fp32 raw partial (no bias), C is float*
// SWZ 1: bijective XCD swizzle for the fixed (64,16) GEMM1 grid (nwg=1024),
//        8x8-tile panels per XCD so co-resident blocks share A rows + B panels.
//
// Pipeline invariants (verified by counting, per-wave vmcnt semantics):
//  - stage(t) -> buf[t&3], 4 global_load_lds per thread per tile
//  - prologue issues stage(0..2); loop iter t issues stage(t+3) if t+3<NT
//  - at iter t entry, in-flight stages = {t .. min(t+2,NT-1)}:
//      t<=NT-3: 12 loads -> vmcnt(8) retires exactly stage(t)
//      t==NT-2:  8 loads -> vmcnt(4);  t==NT-1: 4 loads -> vmcnt(0)
//  - barrier AFTER vmcnt => all waves' portions of buf[t] landed before any
//    ds_read of tile t; end-of-tile barrier (reads all consumed by MFMAs,
//    lgkm auto-drained) orders buf[(t+3)&3] overwrite after tile t-1 reads.
// ---------------------------------------------------------------------------
template <int EPI, int SWZ>
__global__ __launch_bounds__(512, 2)
void gemm256_kernel(const u16* __restrict__ A, int lda,
                    const u16* __restrict__ B, int ldb,
                    int K,
                    const float* __restrict__ bias,
                    void* __restrict__ Cout, int ldc, size_t c_slab) {
    __shared__ __align__(16) u16 As[4 * 8192];   // 4 bufs x 256x32 bf16 = 64 KB
    __shared__ __align__(16) u16 Bs[4 * 8192];   // 64 KB

    const int tid = threadIdx.x;                 // 0..511

    int bx = blockIdx.x, by = blockIdx.y;
    if (SWZ) {
        // grid is (64,16) = 1024 wgs; 1024 % 8 == 0 -> simple bijective swizzle
        const int lin   = by * (int)gridDim.x + bx;  // dispatch order, x fastest
        const int xcd   = lin & 7;                   // round-robin XCD assignment
        const int wg    = xcd * 128 + (lin >> 3);    // contiguous 128 ids / XCD
        const int panel = wg >> 6;                   // 16 panels of 8x8 tiles
        const int within = wg & 63;
        bx = (panel >> 1) * 8 + (within & 7);        // 0..63
        by = (panel & 1) * 8 + (within >> 3);        // 0..15
    }
    const int m0 = by * 256;
    const int n0 = bx * 256;
    const int kz = blockIdx.z;

    A += (size_t)kz * K;
    B += (size_t)kz * K;

    // ---- staging: thread owns chunk (row sr, phys slot sq) and row sr+128.
    // phys slot sq holds global 16B-chunk swz(sq,row); swz(q,r)==swz(q,r+128).
    const int sr = tid >> 2;                 // 0..127
    const int sq = tid & 3;
    const int qg = swz(sq, sr);
    const u16* ga0 = A + (size_t)(m0 + sr) * lda + qg * 8;
    const u16* ga1 = ga0 + (size_t)128 * lda;
    const u16* gb0 = B + (size_t)(n0 + sr) * ldb + qg * 8;
    const u16* gb1 = gb0 + (size_t)128 * ldb;

#define STAGE4(cb) do {                                  \
        async_load16(ga0, &As[(cb) + tid * 8]);          \
        async_load16(ga1, &As[(cb) + 4096 + tid * 8]);   \
        async_load16(gb0, &Bs[(cb) + tid * 8]);          \
        async_load16(gb1, &Bs[(cb) + 4096 + tid * 8]);   \
        ga0 += 32; ga1 += 32; gb0 += 32; gb1 += 32;      \
    } while (0)

    // ---- wave -> output subtile: 2 m-waves x 4 n-waves, 128x64 per wave
    const int wave = tid >> 6;
    const int wm   = wave >> 2;              // 0..1
    const int wn   = wave & 3;               // 0..3
    const int lane = tid & 63;
    const int ln16 = lane & 15;
    const int quad = lane >> 4;

    // loop-invariant swizzled LDS read offsets (u16 units)
    int aoff[8], boff[4];
#pragma unroll
    for (int i = 0; i < 8; ++i) {
        const int ra = wm * 128 + i * 16 + ln16;
        aoff[i] = ra * 32 + swz(quad, ra) * 8;
    }
#pragma unroll
    for (int j = 0; j < 4; ++j) {
        const int rb = wn * 64 + j * 16 + ln16;
        boff[j] = rb * 32 + swz(quad, rb) * 8;
    }

    f32x4 acc[8][4] = {};

    // prologue: 3 tiles in flight
    STAGE4(0);
    STAGE4(8192);
    STAGE4(16384);

    const int NT = K >> 5;                   // BK = 32
    for (int t = 0; t < NT; ++t) {
        if (t < NT - 2)       asm volatile("s_waitcnt vmcnt(8)" ::: "memory");
        else if (t == NT - 2) asm volatile("s_waitcnt vmcnt(4)" ::: "memory");
        else                  asm volatile("s_waitcnt vmcnt(0)" ::: "memory");
        asm volatile("s_barrier" ::: "memory");

        const int cb = (t & 3) * 8192;
        bf16x8 a[8], b[4];
#pragma unroll
        for (int i = 0; i < 8; ++i) a[i] = *(const bf16x8*)&As[cb + aoff[i]];
#pragma unroll
        for (int j = 0; j < 4; ++j) b[j] = *(const bf16x8*)&Bs[cb + boff[j]];

        if (t + 3 < NT) STAGE4(((t + 3) & 3) * 8192);

        __builtin_amdgcn_s_setprio(1);
#pragma unroll
        for (int i = 0; i < 8; ++i)
#pragma unroll
            for (int j = 0; j < 4; ++j)
                acc[i][j] = __builtin_amdgcn_mfma_f32_16x16x32_bf16(
                    a[i], b[j], acc[i][j], 0, 0, 0);
        __builtin_amdgcn_s_setprio(0);

        asm volatile("s_barrier" ::: "memory");
    }
#undef STAGE4

    // epilogue: C/D layout col = lane&15, row = quad*4 + reg (verified)
    if (EPI == 0) {
        u16* C = (u16*)Cout;
#pragma unroll
        for (int j = 0; j < 4; ++j) {
            const int col = n0 + wn * 64 + j * 16 + ln16;
            const float bv = bias[col];
#pragma unroll
            for (int i = 0; i < 8; ++i) {
#pragma unroll
                for (int r = 0; r < 4; ++r) {
                    const int row = m0 + wm * 128 + i * 16 + quad * 4 + r;
                    float v = acc[i][j][r] + bv;
                    v = v > 0.0f ? v : 0.0f;
                    C[(size_t)row * ldc + col] = f2bf(v);
                }
            }
        }
    } else {
        float* C = (float*)Cout + (size_t)kz * c_slab;
#pragma unroll
        for (int j = 0; j < 4; ++j) {
            const int col = n0 + wn * 64 + j * 16 + ln16;
#pragma unroll
            for (int i = 0; i < 8; ++i) {
#pragma unroll
                for (int r = 0; r < 4; ++r) {
                    const int row = m0 + wm * 128 + i * 16 + quad * 4 + r;
                    C[(size_t)row * ldc + col] = acc[i][j][r];
                }
            }
        }
    }
}

// out[m][n] = b2[n] + sum_{kz<4} part[kz][m][n], n < 1000 (float4 over n)
__global__ void reduce_out_kernel(const float* __restrict__ part,
                                  const float* __restrict__ b2,
                                  float* __restrict__ out) {
    const int idx = blockIdx.x * 256 + threadIdx.x;   // 4096*250
    const int m  = idx / 250;
    const int n4 = (idx % 250) * 4;
    const size_t slab = (size_t)4096 * 1024;
    const size_t off = (size_t)m * 1024 + n4;
    float4 s  = *(const float4*)&part[off];
    float4 p1 = *(const float4*)&part[slab + off];
    float4 p2 = *(const float4*)&part[2 * slab + off];
    float4 p3 = *(const float4*)&part[3 * slab + off];
    float4 bv = *(const float4*)&b2[n4];
    s.x += p1.x + p2.x + p3.x + bv.x;
    s.y += p1.y + p2.y + p3.y + bv.y;
    s.z += p1.z + p2.z + p3.z + bv.z;
    s.w += p1.w + p2.w + p3.w + bv.w;
    *(float4*)&out[(size_t)m * 1000 + n4] = s;
}

// ---------------------------------------------------------------------------

extern "C" void kernel_launch(void* const* d_in, const int* in_sizes, int n_in,
                              void* d_out, int out_size, void* d_ws, size_t ws_size,
                              hipStream_t stream) {
    const float* x  = (const float*)d_in[0];   // [4096, 4096]
    const float* W1 = (const float*)d_in[1];   // [16384, 4096]
    const float* b1 = (const float*)d_in[2];   // [16384]
    const float* W2 = (const float*)d_in[3];   // [1000, 20480]
    const float* b2 = (const float*)d_in[4];   // [1000]
    float* out = (float*)d_out;                // [4096, 1000]

    // workspace layout (bf16 elems)
    u16* concat = (u16*)d_ws;                        // [4096][20480]  167.8 MB
    u16* W1b = concat + (size_t)4096 * 20480;        // [16384][4096]  134.2 MB
    u16* W2b = W1b + (size_t)16384 * 4096;           // [1024][20480]   41.9 MB
    // partials reuse W1b region (free after GEMM1): 4*4096*1024 fp32 = 67 MB
    float* partials = (float*)W1b;

    cvt_x_kernel   <<<16384, 256, 0, stream>>>(x, concat);
    cvt_flat_kernel<<<65536, 256, 0, stream>>>(W1, W1b);
    cvt_w2_kernel  <<<20480, 256, 0, stream>>>(W2, W2b);

    // GEMM1: h1 = relu(x @ W1^T + b1) -> concat cols [4096, 20480)
    dim3 g1(16384 / 256, 4096 / 256, 1);   // (64, 16, 1) = 1024 wgs
    gemm256_kernel<0, 1><<<g1, 512, 0, stream>>>(
        concat, 20480, W1b, 4096, 4096, b1, concat + 4096, 20480, 0);

    // GEMM2 split-K=4: partials[kz] = concat[:, kz*5120:(kz+1)*5120] @ W2^T
    dim3 g2(1024 / 256, 4096 / 256, 4);    // (4, 16, 4) = 256 wgs = 1/CU
    gemm256_kernel<1, 0><<<g2, 512, 0, stream>>>(
        concat, 20480, W2b, 20480, 5120, nullptr, partials, 1024,
        (size_t)4096 * 1024);

    // out = b2 + sum partials
    reduce_out_kernel<<<4000, 256, 0, stream>>>(partials, b2, out);
}